// Round 4
// baseline (11992.182 us; speedup 1.0000x reference)
//
#include <hip/hip_runtime.h>
#include <hip/hip_bf16.h>

// Problem constants (from reference)
#define NN 200000   // nodes
#define EE 200000   // edges per pre/suc scale
#define ELR 50000   // left/right edges
#define TOTE 2500000        // 12*EE + 2*ELR
#define MTOT 2800000        // 14 * NN  (CSR key space)
// D = 128, S = 6, L = 4

typedef __attribute__((ext_vector_type(8))) short bf16x8;
typedef __attribute__((ext_vector_type(4))) float f32x4;

__device__ __forceinline__ unsigned short f2bf(float f) {
    unsigned int u = __float_as_uint(f);
    u += 0x7FFFu + ((u >> 16) & 1u);     // RNE
    return (unsigned short)(u >> 16);
}
__device__ __forceinline__ float bf2f(unsigned short s) {
    return __uint_as_float(((unsigned int)s) << 16);
}
__device__ __forceinline__ bf16x8 ld8(const unsigned short* p) {
    return *reinterpret_cast<const bf16x8*>(p);
}

// ---------------------------------------------------------------------------
// Cast all [128,128] weights to bf16 in MFMA B-FRAGMENT ORDER:
// short index (slot, (ks*8+nf)*64 + lane, j8) holds W[ks*32+(lane>>4)*8+j8][nf*16+(lane&15)].
// Slots: 0 Wi2, 1 Ws2, 2+i W_ctr[i], 6+i*6+j W_pre[i][j], 30+i*6+j W_suc[i][j],
//        54+i W_left[i], 58+i W_right[i], 62+i W_ctr2[i].  66 slots.
// ---------------------------------------------------------------------------
__global__ void k_wt(const float* __restrict__ Wi2, const float* __restrict__ Ws2,
                     const float* __restrict__ W_ctr, const float* __restrict__ W_pre,
                     const float* __restrict__ W_suc, const float* __restrict__ W_left,
                     const float* __restrict__ W_right, const float* __restrict__ W_ctr2,
                     unsigned short* __restrict__ Wt) {
    int slot = blockIdx.x;
    const float* src;
    if (slot == 0)        src = Wi2;
    else if (slot == 1)   src = Ws2;
    else if (slot < 6)    src = W_ctr   + (slot - 2)  * 16384;
    else if (slot < 30)   src = W_pre   + (slot - 6)  * 16384;
    else if (slot < 54)   src = W_suc   + (slot - 30) * 16384;
    else if (slot < 58)   src = W_left  + (slot - 54) * 16384;
    else if (slot < 62)   src = W_right + (slot - 58) * 16384;
    else                  src = W_ctr2  + (slot - 62) * 16384;
    unsigned short* dst = Wt + slot * 16384;
    for (int d = threadIdx.x; d < 2048; d += 256) {   // d = octet index (f*64 + lane)
        int f = d >> 6, l = d & 63;
        int ks = f >> 3, nf = f & 7;
        int k0 = ks * 32 + (l >> 4) * 8, n = nf * 16 + (l & 15);
        bf16x8 o;
#pragma unroll
        for (int j8 = 0; j8 < 8; j8++) o[j8] = (short)f2bf(src[(k0 + j8) * 128 + n]);
        *reinterpret_cast<bf16x8*>(dst + d * 8) = o;
    }
}

// ---------------------------------------------------------------------------
// H = relu(xy @ W1 + b1) as bf16 [N,128].  16 threads per node, 8 cols each.
// ---------------------------------------------------------------------------
__global__ void k_in(const float* __restrict__ xy, const float* __restrict__ W1,
                     const float* __restrict__ b1, unsigned short* __restrict__ H) {
    int t = threadIdx.x;
    int node = blockIdx.x * 16 + (t >> 4);
    int dc = (t & 15) * 8;
    float c0 = xy[node * 2], c1 = xy[node * 2 + 1];
    bf16x8 o;
#pragma unroll
    for (int j = 0; j < 8; j++) {
        int d = dc + j;
        float h = fmaf(c0, W1[d], fmaf(c1, W1[128 + d], b1[d]));
        o[j] = (short)f2bf(fmaxf(h, 0.f));
    }
    *reinterpret_cast<bf16x8*>(H + node * 128 + dc) = o;
}

// ---------------------------------------------------------------------------
// Dense GEMM with W resident in VGPRs (input MLP stage only).
// MODE 1: GN(acc; g,b) -> store fp32 out
// MODE 2: GN + resF(fp32) -> relu -> outb bf16
// ---------------------------------------------------------------------------
template <int MODE>
__global__ __launch_bounds__(256, 2)
void k_gemm(const unsigned short* __restrict__ Bfeat, const unsigned short* __restrict__ Wt,
            float* __restrict__ out, const float* __restrict__ resF,
            unsigned short* __restrict__ outb,
            const float* __restrict__ g, const float* __restrict__ bb, int nrows) {
    int wid = threadIdx.x >> 6, lane = threadIdx.x & 63;
    int p = lane & 15, q = lane >> 4;

    bf16x8 bw[4][8];
#pragma unroll
    for (int ks = 0; ks < 4; ks++)
#pragma unroll
        for (int nf = 0; nf < 8; nf++)
            bw[ks][nf] = ld8(Wt + ((ks * 8 + nf) * 64 + lane) * 8);

    float gv[8], bv[8];
#pragma unroll
    for (int nf = 0; nf < 8; nf++) { gv[nf] = g[nf * 16 + p]; bv[nf] = bb[nf * 16 + p]; }

    int waveBase = (blockIdx.x * 4 + wid) * 64;   // 4 chunks of 16 rows per wave
#pragma unroll 1
    for (int c = 0; c < 4; c++) {
        int rb = waveBase + c * 16;
        if (rb >= nrows) break;
        int ra = rb + p; if (ra > nrows - 1) ra = nrows - 1;
        bf16x8 a[4];
#pragma unroll
        for (int ks = 0; ks < 4; ks++)
            a[ks] = ld8(Bfeat + ra * 128 + ks * 32 + q * 8);
        f32x4 acc[8];
#pragma unroll
        for (int nf = 0; nf < 8; nf++) acc[nf] = (f32x4){0.f, 0.f, 0.f, 0.f};
#pragma unroll
        for (int ks = 0; ks < 4; ks++)
#pragma unroll
            for (int nf = 0; nf < 8; nf++)
                acc[nf] = __builtin_amdgcn_mfma_f32_16x16x32_bf16(a[ks], bw[ks][nf], acc[nf], 0, 0, 0);

        float s[4], s2[4];
#pragma unroll
        for (int reg = 0; reg < 4; reg++) {
            s[reg] = 0.f; s2[reg] = 0.f;
#pragma unroll
            for (int nf = 0; nf < 8; nf++) { float v = acc[nf][reg]; s[reg] += v; s2[reg] += v * v; }
        }
#pragma unroll
        for (int m = 1; m <= 8; m <<= 1) {
#pragma unroll
            for (int reg = 0; reg < 4; reg++) {
                s[reg]  += __shfl_xor(s[reg],  m, 64);
                s2[reg] += __shfl_xor(s2[reg], m, 64);
            }
        }
#pragma unroll
        for (int reg = 0; reg < 4; reg++) {
            int row = rb + q * 4 + reg;
            float mean = s[reg] * (1.f / 128.f);
            float var  = s2[reg] * (1.f / 128.f) - mean * mean;
            float rstd = rsqrtf(var + 1e-5f);
            if (row < nrows) {
#pragma unroll
                for (int nf = 0; nf < 8; nf++) {
                    int col = nf * 16 + p;
                    float val = (acc[nf][reg] - mean) * rstd * gv[nf] + bv[nf];
                    if (MODE == 2) {
                        val = fmaxf(val + resF[row * 128 + col], 0.f);
                        outb[row * 128 + col] = f2bf(val);
                    } else {
                        out[row * 128 + col] = val;
                    }
                }
            }
        }
    }
}

// ---------------------------------------------------------------------------
// CSR build: histogram -> scan -> scatter.  Combined key = set*NN + u, 14 sets.
// ---------------------------------------------------------------------------
__device__ __forceinline__ void edge_map(int t, const int* pre, const int* suc,
                                         const int* lft, const int* rgt, int& set, int& val) {
    if (t < 1200000)      { set = t / 200000;                 val = pre[t]; }
    else if (t < 2400000) { int r = t - 1200000; set = 6 + r / 200000; val = suc[r]; }
    else if (t < 2450000) { int r = t - 2400000; set = 12;    val = lft[r]; }
    else                  { int r = t - 2450000; set = 13;    val = rgt[r]; }
}

__global__ void k_hist(const int* __restrict__ pre_u, const int* __restrict__ suc_u,
                       const int* __restrict__ left_u, const int* __restrict__ right_u,
                       int* __restrict__ cnt) {
    int t = blockIdx.x * 256 + threadIdx.x;
    if (t >= TOTE) return;
    int set, u;
    edge_map(t, pre_u, suc_u, left_u, right_u, set, u);
    atomicAdd(&cnt[set * NN + u], 1);
}

__global__ void k_scan1(const int* __restrict__ cnt, int* __restrict__ bsum) {
    __shared__ int sh[256];
    int t = threadIdx.x;
    int base = blockIdx.x * 2048 + t * 8;
    int s = 0;
#pragma unroll
    for (int k = 0; k < 8; k++) { int i = base + k; s += (i < MTOT) ? cnt[i] : 0; }
    sh[t] = s; __syncthreads();
    for (int st = 128; st > 0; st >>= 1) {
        if (t < st) sh[t] += sh[t + st];
        __syncthreads();
    }
    if (t == 0) bsum[blockIdx.x] = sh[0];
}

__global__ void k_scan2(int* __restrict__ bsum, int nb) {   // 1 block, 64 threads
    int lane = threadIdx.x;
    int run = 0;
    for (int base = 0; base < nb; base += 64) {
        int i = base + lane;
        int v = (i < nb) ? bsum[i] : 0;
        int x = v;
#pragma unroll
        for (int d = 1; d < 64; d <<= 1) { int y = __shfl_up(x, d, 64); if (lane >= d) x += y; }
        int excl = x - v + run;
        if (i < nb) bsum[i] = excl;
        run += __shfl(x, 63, 64);
    }
}

__global__ void k_scan3(const int* __restrict__ cnt, const int* __restrict__ bsum,
                        int* __restrict__ off, int* __restrict__ cursor) {
    __shared__ int sh[256];
    int t = threadIdx.x;
    int base = blockIdx.x * 2048 + t * 8;
    int c[8]; int ts = 0;
#pragma unroll
    for (int k = 0; k < 8; k++) { int i = base + k; c[k] = (i < MTOT) ? cnt[i] : 0; ts += c[k]; }
    sh[t] = ts; __syncthreads();
    for (int d = 1; d < 256; d <<= 1) {
        int y = (t >= d) ? sh[t - d] : 0;
        __syncthreads();
        sh[t] += y;
        __syncthreads();
    }
    int run = sh[t] - ts + bsum[blockIdx.x];
#pragma unroll
    for (int k = 0; k < 8; k++) {
        int i = base + k;
        if (i < MTOT) { off[i] = run; cursor[i] = run; run += c[k]; }
    }
    if (blockIdx.x == 0 && t == 0) off[MTOT] = TOTE;
}

// Pack u_local (u&15, chunk-relative) into bits 20..23 of the edge entry.
__global__ void k_scatter(const int* __restrict__ pre_u, const int* __restrict__ pre_v,
                          const int* __restrict__ suc_u, const int* __restrict__ suc_v,
                          const int* __restrict__ left_u, const int* __restrict__ left_v,
                          const int* __restrict__ right_u, const int* __restrict__ right_v,
                          int* __restrict__ cursor, int* __restrict__ eidx) {
    int t = blockIdx.x * 256 + threadIdx.x;
    if (t >= TOTE) return;
    int set, u, setv, v;
    edge_map(t, pre_u, suc_u, left_u, right_u, set, u);
    edge_map(t, pre_v, suc_v, left_v, right_v, setv, v);
    int pos = atomicAdd(&cursor[set * NN + u], 1);
    eidx[pos] = v | ((u & 15) << 20);
}

// ---------------------------------------------------------------------------
// Fully-fused fuse iteration (pull-based, cooperative gather, fused ctr2):
//  per 16-row chunk (1 wave, 4 waves/block):
//   acc = feat@Wc + Sum_sets (Sum_{CSR seg} feat[v]) @ W_set     (MFMA)
//   featm = relu(GN1(acc))        -> LDS transpose (wave-local)
//   acc2  = featm @ W_ctr2                                       (MFMA)
//   feat_new = relu(GN2(acc2) + feat_old)  -> dst (bf16)
// LDS accumulator af uses bit-rotated column map  m(c) = (c>>3)|((c&7)<<4),
// stride 17 (row 16 = trash row for masked edges) => ~2-way banks for both
// the ds_add_f32 gather atomics and the A-frag readback.
// ---------------------------------------------------------------------------
__global__ __launch_bounds__(256, 2)
void k_fuse(const unsigned short* __restrict__ src, unsigned short* __restrict__ dst,
            const int* __restrict__ off, const int* __restrict__ eidx,
            const unsigned short* __restrict__ Wt,
            const float* __restrict__ g1, const float* __restrict__ b1,
            const float* __restrict__ g2, const float* __restrict__ b2, int iter) {
    __shared__ __align__(16) unsigned short wlds[16384];   // 32 KB staged W
    __shared__ __align__(16) float afs[4][128 * 17];       // 34.8 KB: per-wave accum
    int tid = threadIdx.x, wid = tid >> 6, lane = tid & 63;
    int p = lane & 15, q = lane >> 4;
    int rb = (blockIdx.x * 4 + wid) * 16;

    f32x4 acc[8];
#pragma unroll
    for (int nf = 0; nf < 8; nf++) acc[nf] = (f32x4){0.f, 0.f, 0.f, 0.f};
    float gv1[8], bv1[8];
#pragma unroll
    for (int nf = 0; nf < 8; nf++) { gv1[nf] = g1[nf * 16 + p]; bv1[nf] = b1[nf * 16 + p]; }

#pragma unroll 1
    for (int j = 0; j < 15; j++) {
        int slot;
        if (j == 0)       slot = 2 + iter;
        else if (j <= 6)  slot = 6 + iter * 6 + (j - 1);
        else if (j <= 12) slot = 30 + iter * 6 + (j - 7);
        else if (j == 13) slot = 54 + iter;
        else              slot = 58 + iter;

        __syncthreads();   // all waves done reading wlds of previous set
#pragma unroll
        for (int k = 0; k < 8; k++)
            *reinterpret_cast<bf16x8*>(wlds + k * 2048 + tid * 8) =
                ld8(Wt + slot * 16384 + k * 2048 + tid * 8);

        bf16x8 afr[4];
        if (j == 0) {
            // ctr contribution: A = feat rows directly
#pragma unroll
            for (int ks = 0; ks < 4; ks++)
                afr[ks] = ld8(src + (rb + p) * 128 + ks * 32 + q * 8);
        } else {
            // zero af (2176 words, wave-local)
            f32x4 z4 = (f32x4){0.f, 0.f, 0.f, 0.f};
#pragma unroll
            for (int z = 0; z < 8; z++)
                *reinterpret_cast<f32x4*>(&afs[wid][z * 256 + lane * 4]) = z4;
            if (lane < 32)
                *reinterpret_cast<f32x4*>(&afs[wid][2048 + lane * 4]) = z4;

            int key = (j - 1) * NN + rb;
            int s0 = off[key], e0 = off[key + 16];
#pragma unroll 1
            for (int base = s0; base < e0; base += 16) {
                int ii = base + (lane & 15); if (ii >= e0) ii = e0 - 1;
                int ent = eidx[ii];
#pragma unroll
                for (int r = 0; r < 4; r++) {
                    int es = r * 4 + q;
                    int pe = __shfl(ent, es, 64);
                    int valid = (base + es) < e0;
                    int v = pe & 0xFFFFF;
                    int ul = valid ? (pe >> 20) : 16;    // 16 = trash row (pad)
                    bf16x8 row = ld8(src + v * 128 + p * 8);
#pragma unroll
                    for (int i2 = 0; i2 < 8; i2++)
                        atomicAdd(&afs[wid][(p + (i2 << 4)) * 17 + ul],
                                  bf2f((unsigned short)row[i2]));
                }
            }
            // A-frag readback: A[row=p][k=ks*32+q*8+jj] at af[m(k)*17+p]
#pragma unroll
            for (int ks = 0; ks < 4; ks++) {
#pragma unroll
                for (int jj = 0; jj < 8; jj++) {
                    float f = afs[wid][((ks * 4 + q) + (jj << 4)) * 17 + p];
                    afr[ks][jj] = (short)f2bf(f);
                }
            }
        }
        __syncthreads();   // wlds staged
#pragma unroll
        for (int ks = 0; ks < 4; ks++)
#pragma unroll
            for (int nf = 0; nf < 8; nf++) {
                bf16x8 bwf = *reinterpret_cast<const bf16x8*>(wlds + ((ks * 8 + nf) * 64 + lane) * 8);
                acc[nf] = __builtin_amdgcn_mfma_f32_16x16x32_bf16(afr[ks], bwf, acc[nf], 0, 0, 0);
            }
    }

    // ---- GN1 + relu -> transposed into af (wave-local) ----
    {
        float s[4], s2[4];
#pragma unroll
        for (int reg = 0; reg < 4; reg++) {
            s[reg] = 0.f; s2[reg] = 0.f;
#pragma unroll
            for (int nf = 0; nf < 8; nf++) { float v = acc[nf][reg]; s[reg] += v; s2[reg] += v * v; }
        }
#pragma unroll
        for (int m = 1; m <= 8; m <<= 1) {
#pragma unroll
            for (int reg = 0; reg < 4; reg++) {
                s[reg]  += __shfl_xor(s[reg],  m, 64);
                s2[reg] += __shfl_xor(s2[reg], m, 64);
            }
        }
#pragma unroll
        for (int reg = 0; reg < 4; reg++) {
            float mean = s[reg] * (1.f / 128.f);
            float var  = s2[reg] * (1.f / 128.f) - mean * mean;
            float rstd = rsqrtf(var + 1e-5f);
            int row = q * 4 + reg;
#pragma unroll
            for (int nf = 0; nf < 8; nf++) {
                float val = fmaxf((acc[nf][reg] - mean) * rstd * gv1[nf] + bv1[nf], 0.f);
                int col = nf * 16 + p;
                int m2 = (col >> 3) + ((col & 7) << 4);
                afs[wid][m2 * 17 + row] = val;
            }
        }
    }

    // ---- stage W_ctr2, load residual ----
    __syncthreads();
#pragma unroll
    for (int k = 0; k < 8; k++)
        *reinterpret_cast<bf16x8*>(wlds + k * 2048 + tid * 8) =
            ld8(Wt + (62 + iter) * 16384 + k * 2048 + tid * 8);
    unsigned short rv[4][8];
#pragma unroll
    for (int reg = 0; reg < 4; reg++)
#pragma unroll
        for (int nf = 0; nf < 8; nf++)
            rv[reg][nf] = src[(rb + q * 4 + reg) * 128 + nf * 16 + p];
    float gv2[8], bv2[8];
#pragma unroll
    for (int nf = 0; nf < 8; nf++) { gv2[nf] = g2[nf * 16 + p]; bv2[nf] = b2[nf * 16 + p]; }
    __syncthreads();

    // ---- ctr2 MFMA ----
    bf16x8 a2[4];
#pragma unroll
    for (int ks = 0; ks < 4; ks++) {
#pragma unroll
        for (int jj = 0; jj < 8; jj++) {
            float f = afs[wid][((ks * 4 + q) + (jj << 4)) * 17 + p];
            a2[ks][jj] = (short)f2bf(f);
        }
    }
#pragma unroll
    for (int nf = 0; nf < 8; nf++) acc[nf] = (f32x4){0.f, 0.f, 0.f, 0.f};
#pragma unroll
    for (int ks = 0; ks < 4; ks++)
#pragma unroll
        for (int nf = 0; nf < 8; nf++) {
            bf16x8 bwf = *reinterpret_cast<const bf16x8*>(wlds + ((ks * 8 + nf) * 64 + lane) * 8);
            acc[nf] = __builtin_amdgcn_mfma_f32_16x16x32_bf16(a2[ks], bwf, acc[nf], 0, 0, 0);
        }

    // ---- GN2 + residual + relu -> dst ----
    {
        float s[4], s2[4];
#pragma unroll
        for (int reg = 0; reg < 4; reg++) {
            s[reg] = 0.f; s2[reg] = 0.f;
#pragma unroll
            for (int nf = 0; nf < 8; nf++) { float v = acc[nf][reg]; s[reg] += v; s2[reg] += v * v; }
        }
#pragma unroll
        for (int m = 1; m <= 8; m <<= 1) {
#pragma unroll
            for (int reg = 0; reg < 4; reg++) {
                s[reg]  += __shfl_xor(s[reg],  m, 64);
                s2[reg] += __shfl_xor(s2[reg], m, 64);
            }
        }
#pragma unroll
        for (int reg = 0; reg < 4; reg++) {
            float mean = s[reg] * (1.f / 128.f);
            float var  = s2[reg] * (1.f / 128.f) - mean * mean;
            float rstd = rsqrtf(var + 1e-5f);
            int row = rb + q * 4 + reg;
#pragma unroll
            for (int nf = 0; nf < 8; nf++) {
                float val = (acc[nf][reg] - mean) * rstd * gv2[nf] + bv2[nf] + bf2f(rv[reg][nf]);
                val = fmaxf(val, 0.f);
                dst[row * 128 + nf * 16 + p] = f2bf(val);
            }
        }
    }
}

// ---------------------------------------------------------------------------
// Final cast: featA (bf16) -> d_out (fp32)
// ---------------------------------------------------------------------------
__global__ void k_copy(const unsigned short* __restrict__ srcb, float* __restrict__ out) {
    int t = blockIdx.x * 256 + threadIdx.x;    // one octet per thread
    bf16x8 v = ld8(srcb + t * 8);
    f32x4 lo, hi;
#pragma unroll
    for (int i = 0; i < 4; i++) { lo[i] = bf2f((unsigned short)v[i]); hi[i] = bf2f((unsigned short)v[i + 4]); }
    *reinterpret_cast<f32x4*>(out + t * 8)     = lo;
    *reinterpret_cast<f32x4*>(out + t * 8 + 4) = hi;
}

// ---------------------------------------------------------------------------
extern "C" void kernel_launch(void* const* d_in, const int* in_sizes, int n_in,
                              void* d_out, int out_size, void* d_ws, size_t ws_size,
                              hipStream_t stream) {
    (void)in_sizes; (void)n_in; (void)out_size; (void)ws_size;
    const float* ctrs   = (const float*)d_in[0];
    const float* feats  = (const float*)d_in[1];
    const float* Wi1    = (const float*)d_in[2];
    const float* bi1    = (const float*)d_in[3];
    const float* Wi2    = (const float*)d_in[4];
    const float* gi     = (const float*)d_in[5];
    const float* bi     = (const float*)d_in[6];
    const float* Ws1    = (const float*)d_in[7];
    const float* bs1    = (const float*)d_in[8];
    const float* Ws2    = (const float*)d_in[9];
    const float* gs     = (const float*)d_in[10];
    const float* bs     = (const float*)d_in[11];
    const float* W_ctr  = (const float*)d_in[12];
    const float* W_pre  = (const float*)d_in[13];
    const float* W_suc  = (const float*)d_in[14];
    const float* W_left = (const float*)d_in[15];
    const float* W_right= (const float*)d_in[16];
    const float* norm_g = (const float*)d_in[17];
    const float* norm_b = (const float*)d_in[18];
    const float* W_ctr2 = (const float*)d_in[19];
    const float* ctr2_g = (const float*)d_in[20];
    const float* ctr2_b = (const float*)d_in[21];
    const int* pre_u  = (const int*)d_in[22];
    const int* pre_v  = (const int*)d_in[23];
    const int* suc_u  = (const int*)d_in[24];
    const int* suc_v  = (const int*)d_in[25];
    const int* left_u = (const int*)d_in[26];
    const int* left_v = (const int*)d_in[27];
    const int* right_u= (const int*)d_in[28];
    const int* right_v= (const int*)d_in[29];

    // ws layout (85.8 MB total):
    //   Wt     @ 0          (2,162,688 B)
    //   off    @ 2,162,688  (11,200,016 B)   [cnt aliases off during histogram]
    //   eidx   @ 13,362,704 (10,000,000 B)
    //   featA  @ 23,362,704 (51,200,000 B)
    //   cursor @ 74,562,704 (11,200,016 B)   [dead after k_scatter]
    //   bsum   @ 85,762,720 (8,192 B)
    char* ws = (char*)d_ws;
    unsigned short* Wt    = (unsigned short*)ws;
    int*            off   = (int*)(ws + 2162688);
    int*            cnt   = off;
    int*            eidx  = (int*)(ws + 13362704);
    unsigned short* featA = (unsigned short*)(ws + 23362704);
    int*            cursor= (int*)(ws + 74562704);
    int*            bsum  = (int*)(ws + 85762720);

    // d_out (102.4 MB fp32): input-stage fp32 temp, then featB (bf16, first half),
    // finally the fp32 output (k_copy).
    float*          outF  = (float*)d_out;
    unsigned short* featB = (unsigned short*)d_out;

    const int GEMM_GRID = (NN + 255) / 256;       // 782
    const int NB_SCAN   = (MTOT + 2047) / 2048;   // 1368

    k_wt<<<66, 256, 0, stream>>>(Wi2, Ws2, W_ctr, W_pre, W_suc, W_left, W_right, W_ctr2, Wt);

    // Input stage: featA = relu(GN(relu(ctrs@Wi1+bi1)@Wi2) + GN(relu(feats@Ws1+bs1)@Ws2))
    k_in<<<NN / 16, 256, 0, stream>>>(ctrs, Wi1, bi1, featA);
    k_gemm<1><<<GEMM_GRID, 256, 0, stream>>>(featA, Wt + 0 * 16384, outF, nullptr, nullptr, gi, bi, NN);
    k_in<<<NN / 16, 256, 0, stream>>>(feats, Ws1, bs1, featA);
    k_gemm<2><<<GEMM_GRID, 256, 0, stream>>>(featA, Wt + 1 * 16384, nullptr, outF, featA, gs, bs, NN);

    // CSR build (ws scratch)
    hipMemsetAsync(cnt, 0, (MTOT + 1) * sizeof(int), stream);
    k_hist<<<(TOTE + 255) / 256, 256, 0, stream>>>(pre_u, suc_u, left_u, right_u, cnt);
    k_scan1<<<NB_SCAN, 256, 0, stream>>>(cnt, bsum);
    k_scan2<<<1, 64, 0, stream>>>(bsum, NB_SCAN);
    k_scan3<<<NB_SCAN, 256, 0, stream>>>(cnt, bsum, off, cursor);
    k_scatter<<<(TOTE + 255) / 256, 256, 0, stream>>>(pre_u, pre_v, suc_u, suc_v,
                                                      left_u, left_v, right_u, right_v,
                                                      cursor, eidx);

    // 4 fuse iterations, ping-pong featA (ws) <-> featB (d_out)
    const unsigned short* fs[5] = { featA, featB, featA, featB, featA };
    for (int i = 0; i < 4; i++) {
        k_fuse<<<NN / 64, 256, 0, stream>>>(fs[i], (unsigned short*)fs[i + 1],
                                            off, eidx, Wt,
                                            norm_g + i * 128, norm_b + i * 128,
                                            ctr2_g + i * 128, ctr2_b + i * 128, i);
    }
    // final: featA -> fp32 d_out
    k_copy<<<NN * 128 / (256 * 8), 256, 0, stream>>>(featA, outF);
}

// Round 5
// 1908.538 us; speedup vs baseline: 6.2834x; 6.2834x over previous
//
#include <hip/hip_runtime.h>
#include <hip/hip_bf16.h>

// Problem constants (from reference)
#define NN 200000   // nodes
#define EE 200000   // edges per pre/suc scale
#define ELR 50000   // left/right edges
#define TOTE 2500000        // 12*EE + 2*ELR
#define MTOT 2800000        // 14 * NN  (CSR key space)
// D = 128, S = 6, L = 4

typedef __attribute__((ext_vector_type(8))) short bf16x8;
typedef __attribute__((ext_vector_type(4))) float f32x4;

__device__ __forceinline__ unsigned short f2bf(float f) {
    unsigned int u = __float_as_uint(f);
    u += 0x7FFFu + ((u >> 16) & 1u);     // RNE
    return (unsigned short)(u >> 16);
}
__device__ __forceinline__ float bf2f(unsigned short s) {
    return __uint_as_float(((unsigned int)s) << 16);
}
__device__ __forceinline__ bf16x8 ld8(const unsigned short* p) {
    return *reinterpret_cast<const bf16x8*>(p);
}

// Slot map: 0 Wi2, 1 Ws2, 2+i W_ctr[i], 6+i*6+k W_pre[i][k], 30+i*6+(k-6) W_suc,
//           54+i W_left[i], 58+i W_right[i], 62+i W_ctr2[i].  66 slots.
__device__ __forceinline__ int slot_of(int j, int iter) {
    // j = fuse set index 0..14; 0=ctr, 1..14 = CSR key j-1
    if (j == 0) return 2 + iter;
    int k = j - 1;
    if (k < 6)   return 6 + iter * 6 + k;
    if (k < 12)  return 30 + iter * 6 + (k - 6);
    if (k == 12) return 54 + iter;
    return 58 + iter;
}

// ---------------------------------------------------------------------------
// Cast all [128,128] weights to bf16 in MFMA B-FRAGMENT ORDER:
// short index (slot, (ks*8+nf)*64 + lane, j8) holds W[ks*32+(lane>>4)*8+j8][nf*16+(lane&15)].
// ---------------------------------------------------------------------------
__global__ void k_wt(const float* __restrict__ Wi2, const float* __restrict__ Ws2,
                     const float* __restrict__ W_ctr, const float* __restrict__ W_pre,
                     const float* __restrict__ W_suc, const float* __restrict__ W_left,
                     const float* __restrict__ W_right, const float* __restrict__ W_ctr2,
                     unsigned short* __restrict__ Wt) {
    int slot = blockIdx.x;
    const float* src;
    if (slot == 0)        src = Wi2;
    else if (slot == 1)   src = Ws2;
    else if (slot < 6)    src = W_ctr   + (slot - 2)  * 16384;
    else if (slot < 30)   src = W_pre   + (slot - 6)  * 16384;
    else if (slot < 54)   src = W_suc   + (slot - 30) * 16384;
    else if (slot < 58)   src = W_left  + (slot - 54) * 16384;
    else if (slot < 62)   src = W_right + (slot - 58) * 16384;
    else                  src = W_ctr2  + (slot - 62) * 16384;
    unsigned short* dst = Wt + slot * 16384;
    for (int d = threadIdx.x; d < 2048; d += 256) {   // d = octet index (f*64 + lane)
        int f = d >> 6, l = d & 63;
        int ks = f >> 3, nf = f & 7;
        int k0 = ks * 32 + (l >> 4) * 8, n = nf * 16 + (l & 15);
        bf16x8 o;
#pragma unroll
        for (int j8 = 0; j8 < 8; j8++) o[j8] = (short)f2bf(src[(k0 + j8) * 128 + n]);
        *reinterpret_cast<bf16x8*>(dst + d * 8) = o;
    }
}

// ---------------------------------------------------------------------------
// Fused input MLP: featA = relu( GN(relu(ctrs@Wi1+bi1)@Wi2; gi,bi)
//                              + GN(relu(feats@Ws1+bs1)@Ws2; gs,bs) )  [bf16]
// 4 waves x 16-row chunks; H fragments computed in-register; Wi2/Ws2 staged.
// ---------------------------------------------------------------------------
__global__ __launch_bounds__(256, 4)
void k_input(const float* __restrict__ ctrs, const float* __restrict__ feats,
             const float* __restrict__ Wi1, const float* __restrict__ bi1,
             const float* __restrict__ gi, const float* __restrict__ bi,
             const float* __restrict__ Ws1, const float* __restrict__ bs1,
             const float* __restrict__ gs, const float* __restrict__ bs,
             const unsigned short* __restrict__ Wt, unsigned short* __restrict__ featA) {
    __shared__ __align__(16) unsigned short wlds[16384];
    int tid = threadIdx.x, wid = tid >> 6, lane = tid & 63;
    int p = lane & 15, q = lane >> 4;
    int rb = (blockIdx.x * 4 + wid) * 16;
    int row = rb + p;

    float c0 = ctrs[row * 2], c1 = ctrs[row * 2 + 1];
    float d0 = feats[row * 2], d1 = feats[row * 2 + 1];

    // ---- phase 1: Wi2, H1 = relu(ctrs@Wi1+bi1) ----
#pragma unroll
    for (int k = 0; k < 8; k++)
        *reinterpret_cast<bf16x8*>(wlds + k * 2048 + tid * 8) =
            ld8(Wt + 0 * 16384 + k * 2048 + tid * 8);
    bf16x8 a1[4];
#pragma unroll
    for (int ks = 0; ks < 4; ks++)
#pragma unroll
        for (int jj = 0; jj < 8; jj++) {
            int k = ks * 32 + q * 8 + jj;
            float h = fmaf(c0, Wi1[k], fmaf(c1, Wi1[128 + k], bi1[k]));
            a1[ks][jj] = (short)f2bf(fmaxf(h, 0.f));
        }
    __syncthreads();
    f32x4 acc[8];
#pragma unroll
    for (int nf = 0; nf < 8; nf++) acc[nf] = (f32x4){0.f, 0.f, 0.f, 0.f};
#pragma unroll
    for (int ks = 0; ks < 4; ks++)
#pragma unroll
        for (int nf = 0; nf < 8; nf++) {
            bf16x8 bwf = *reinterpret_cast<const bf16x8*>(wlds + ((ks * 8 + nf) * 64 + lane) * 8);
            acc[nf] = __builtin_amdgcn_mfma_f32_16x16x32_bf16(a1[ks], bwf, acc[nf], 0, 0, 0);
        }
    // GN1 -> v1 regs
    float v1[4][8];
    {
        float s[4], s2[4];
#pragma unroll
        for (int reg = 0; reg < 4; reg++) {
            s[reg] = 0.f; s2[reg] = 0.f;
#pragma unroll
            for (int nf = 0; nf < 8; nf++) { float v = acc[nf][reg]; s[reg] += v; s2[reg] += v * v; }
        }
#pragma unroll
        for (int m = 1; m <= 8; m <<= 1) {
#pragma unroll
            for (int reg = 0; reg < 4; reg++) {
                s[reg]  += __shfl_xor(s[reg],  m, 64);
                s2[reg] += __shfl_xor(s2[reg], m, 64);
            }
        }
#pragma unroll
        for (int reg = 0; reg < 4; reg++) {
            float mean = s[reg] * (1.f / 128.f);
            float var  = s2[reg] * (1.f / 128.f) - mean * mean;
            float rstd = rsqrtf(var + 1e-5f);
#pragma unroll
            for (int nf = 0; nf < 8; nf++)
                v1[reg][nf] = (acc[nf][reg] - mean) * rstd * gi[nf * 16 + p] + bi[nf * 16 + p];
        }
    }
    __syncthreads();   // wlds consumed

    // ---- phase 2: Ws2, H2 = relu(feats@Ws1+bs1) ----
#pragma unroll
    for (int k = 0; k < 8; k++)
        *reinterpret_cast<bf16x8*>(wlds + k * 2048 + tid * 8) =
            ld8(Wt + 1 * 16384 + k * 2048 + tid * 8);
    bf16x8 a2[4];
#pragma unroll
    for (int ks = 0; ks < 4; ks++)
#pragma unroll
        for (int jj = 0; jj < 8; jj++) {
            int k = ks * 32 + q * 8 + jj;
            float h = fmaf(d0, Ws1[k], fmaf(d1, Ws1[128 + k], bs1[k]));
            a2[ks][jj] = (short)f2bf(fmaxf(h, 0.f));
        }
    __syncthreads();
#pragma unroll
    for (int nf = 0; nf < 8; nf++) acc[nf] = (f32x4){0.f, 0.f, 0.f, 0.f};
#pragma unroll
    for (int ks = 0; ks < 4; ks++)
#pragma unroll
        for (int nf = 0; nf < 8; nf++) {
            bf16x8 bwf = *reinterpret_cast<const bf16x8*>(wlds + ((ks * 8 + nf) * 64 + lane) * 8);
            acc[nf] = __builtin_amdgcn_mfma_f32_16x16x32_bf16(a2[ks], bwf, acc[nf], 0, 0, 0);
        }
    // GN2 + add + relu -> store
    {
        float s[4], s2[4];
#pragma unroll
        for (int reg = 0; reg < 4; reg++) {
            s[reg] = 0.f; s2[reg] = 0.f;
#pragma unroll
            for (int nf = 0; nf < 8; nf++) { float v = acc[nf][reg]; s[reg] += v; s2[reg] += v * v; }
        }
#pragma unroll
        for (int m = 1; m <= 8; m <<= 1) {
#pragma unroll
            for (int reg = 0; reg < 4; reg++) {
                s[reg]  += __shfl_xor(s[reg],  m, 64);
                s2[reg] += __shfl_xor(s2[reg], m, 64);
            }
        }
#pragma unroll
        for (int reg = 0; reg < 4; reg++) {
            float mean = s[reg] * (1.f / 128.f);
            float var  = s2[reg] * (1.f / 128.f) - mean * mean;
            float rstd = rsqrtf(var + 1e-5f);
            int r2 = rb + q * 4 + reg;
#pragma unroll
            for (int nf = 0; nf < 8; nf++) {
                float g2 = (acc[nf][reg] - mean) * rstd * gs[nf * 16 + p] + bs[nf * 16 + p];
                float val = fmaxf(v1[reg][nf] + g2, 0.f);
                featA[r2 * 128 + nf * 16 + p] = f2bf(val);
            }
        }
    }
}

// ---------------------------------------------------------------------------
// CSR build: histogram -> scan -> scatter.  Combined key = set*NN + u, 14 sets.
// ---------------------------------------------------------------------------
__device__ __forceinline__ void edge_map(int t, const int* pre, const int* suc,
                                         const int* lft, const int* rgt, int& set, int& val) {
    if (t < 1200000)      { set = t / 200000;                 val = pre[t]; }
    else if (t < 2400000) { int r = t - 1200000; set = 6 + r / 200000; val = suc[r]; }
    else if (t < 2450000) { int r = t - 2400000; set = 12;    val = lft[r]; }
    else                  { int r = t - 2450000; set = 13;    val = rgt[r]; }
}

__global__ void k_hist(const int* __restrict__ pre_u, const int* __restrict__ suc_u,
                       const int* __restrict__ left_u, const int* __restrict__ right_u,
                       int* __restrict__ cnt) {
    int t = blockIdx.x * 256 + threadIdx.x;
    if (t >= TOTE) return;
    int set, u;
    edge_map(t, pre_u, suc_u, left_u, right_u, set, u);
    atomicAdd(&cnt[set * NN + u], 1);
}

__global__ void k_scan1(const int* __restrict__ cnt, int* __restrict__ bsum) {
    __shared__ int sh[256];
    int t = threadIdx.x;
    int base = blockIdx.x * 2048 + t * 8;
    int s = 0;
#pragma unroll
    for (int k = 0; k < 8; k++) { int i = base + k; s += (i < MTOT) ? cnt[i] : 0; }
    sh[t] = s; __syncthreads();
    for (int st = 128; st > 0; st >>= 1) {
        if (t < st) sh[t] += sh[t + st];
        __syncthreads();
    }
    if (t == 0) bsum[blockIdx.x] = sh[0];
}

__global__ void k_scan2(int* __restrict__ bsum, int nb) {   // 1 block, 64 threads
    int lane = threadIdx.x;
    int run = 0;
    for (int base = 0; base < nb; base += 64) {
        int i = base + lane;
        int v = (i < nb) ? bsum[i] : 0;
        int x = v;
#pragma unroll
        for (int d = 1; d < 64; d <<= 1) { int y = __shfl_up(x, d, 64); if (lane >= d) x += y; }
        int excl = x - v + run;
        if (i < nb) bsum[i] = excl;
        run += __shfl(x, 63, 64);
    }
}

__global__ void k_scan3(const int* __restrict__ cnt, const int* __restrict__ bsum,
                        int* __restrict__ off, int* __restrict__ cursor) {
    __shared__ int sh[256];
    int t = threadIdx.x;
    int base = blockIdx.x * 2048 + t * 8;
    int c[8]; int ts = 0;
#pragma unroll
    for (int k = 0; k < 8; k++) { int i = base + k; c[k] = (i < MTOT) ? cnt[i] : 0; ts += c[k]; }
    sh[t] = ts; __syncthreads();
    for (int d = 1; d < 256; d <<= 1) {
        int y = (t >= d) ? sh[t - d] : 0;
        __syncthreads();
        sh[t] += y;
        __syncthreads();
    }
    int run = sh[t] - ts + bsum[blockIdx.x];
#pragma unroll
    for (int k = 0; k < 8; k++) {
        int i = base + k;
        if (i < MTOT) { off[i] = run; cursor[i] = run; run += c[k]; }
    }
    if (blockIdx.x == 0 && t == 0) off[MTOT] = TOTE;
}

__global__ void k_scatter(const int* __restrict__ pre_u, const int* __restrict__ pre_v,
                          const int* __restrict__ suc_u, const int* __restrict__ suc_v,
                          const int* __restrict__ left_u, const int* __restrict__ left_v,
                          const int* __restrict__ right_u, const int* __restrict__ right_v,
                          int* __restrict__ cursor, int* __restrict__ eidx) {
    int t = blockIdx.x * 256 + threadIdx.x;
    if (t >= TOTE) return;
    int set, u, setv, v;
    edge_map(t, pre_u, suc_u, left_u, right_u, set, u);
    edge_map(t, pre_v, suc_v, left_v, right_v, setv, v);
    int pos = atomicAdd(&cursor[set * NN + u], 1);
    eidx[pos] = v;
}

// ---------------------------------------------------------------------------
// Fused fuse-iteration, 8-wave set-split:
//   waves 0-3 (group 0): chunk wid, fuse sets 0..7   (ctr + pre0-5 + suc0)
//   waves 4-7 (group 1): chunk wid&3, fuse sets 8..14 (suc1-5 + left + right)
// 8 lock-step phases {barrier; stage W[g]; gather; barrier; MFMA}, then
// LDS f32 combine (g1 acc -> g0), GN1+relu -> bf16 LDS transpose (stride 136),
// ctr2 MFMA, GN2 + residual + relu -> dst.  Gather = round-2 per-lane walk.
// LDS: [0,32KB) = wldsA (g0 W; later W_ctr2); [32KB,64KB) = wldsB (g1 W;
// later f32 combine, then bf16 transpose buffer).
// ---------------------------------------------------------------------------
__global__ __launch_bounds__(512, 4)
void k_fuse(const unsigned short* __restrict__ src, unsigned short* __restrict__ dst,
            const int* __restrict__ off, const int* __restrict__ eidx,
            const unsigned short* __restrict__ Wt,
            const float* __restrict__ g1v, const float* __restrict__ b1v,
            const float* __restrict__ g2v, const float* __restrict__ b2v, int iter) {
    __shared__ __align__(16) unsigned short lds[32768];    // 64 KB
    int tid = threadIdx.x, wid = tid >> 6, lane = tid & 63;
    int p = lane & 15, q = lane >> 4;
    int g = tid >> 8;                 // 0: waves 0-3, 1: waves 4-7
    int tg = tid & 255;               // tid within group
    int chunk = wid & 3;
    int rb = (blockIdx.x * 4 + chunk) * 16;
    unsigned short* wlds = lds + g * 16384;

    f32x4 acc[8];
#pragma unroll
    for (int nf = 0; nf < 8; nf++) acc[nf] = (f32x4){0.f, 0.f, 0.f, 0.f};

#pragma unroll 1
    for (int t = 0; t < 8; t++) {
        int active = (g == 0) || (t < 7);
        int j = (g == 0) ? t : (8 + t);
        __syncthreads();   // wlds[g] free (prev MFMA done in all waves)
        if (active) {
            int slot = slot_of(j, iter);
#pragma unroll
            for (int k = 0; k < 8; k++)
                *reinterpret_cast<bf16x8*>(wlds + k * 2048 + tg * 8) =
                    ld8(Wt + slot * 16384 + k * 2048 + tg * 8);
        } else {
            // g1, t==7: publish acc into combine buffer (aliases wldsB; g1's
            // own W reads finished at t==6 MFMA, nobody stages wldsB now)
            float* comb = reinterpret_cast<float*>(lds + 16384);
#pragma unroll
            for (int reg = 0; reg < 4; reg++)
#pragma unroll
                for (int nf = 0; nf < 8; nf++)
                    comb[chunk * 2048 + (q * 4 + reg) * 128 + nf * 16 + p] = acc[nf][reg];
        }
        bf16x8 afr[4];
        if (active) {
            if (j == 0) {
#pragma unroll
                for (int ks = 0; ks < 4; ks++)
                    afr[ks] = ld8(src + (rb + p) * 128 + ks * 32 + q * 8);
            } else {
                int key = (j - 1) * NN + rb + p;
                int s0 = off[key], e0 = off[key + 1];
                float sa[4][8];
#pragma unroll
                for (int ks = 0; ks < 4; ks++)
#pragma unroll
                    for (int i2 = 0; i2 < 8; i2++) sa[ks][i2] = 0.f;
                for (int t2 = s0; t2 < e0; t2++) {
                    int v = eidx[t2];
#pragma unroll
                    for (int ks = 0; ks < 4; ks++) {
                        bf16x8 r = ld8(src + v * 128 + ks * 32 + q * 8);
#pragma unroll
                        for (int i2 = 0; i2 < 8; i2++) sa[ks][i2] += bf2f((unsigned short)r[i2]);
                    }
                }
#pragma unroll
                for (int ks = 0; ks < 4; ks++)
#pragma unroll
                    for (int i2 = 0; i2 < 8; i2++) afr[ks][i2] = (short)f2bf(sa[ks][i2]);
            }
        }
        __syncthreads();   // wlds[g] staged / combine written
        if (active) {
#pragma unroll
            for (int ks = 0; ks < 4; ks++)
#pragma unroll
                for (int nf = 0; nf < 8; nf++) {
                    bf16x8 bwf = *reinterpret_cast<const bf16x8*>(wlds + ((ks * 8 + nf) * 64 + lane) * 8);
                    acc[nf] = __builtin_amdgcn_mfma_f32_16x16x32_bf16(afr[ks], bwf, acc[nf], 0, 0, 0);
                }
        }
    }

    __syncthreads();   // phase-7 MFMA (g0, wldsA) done; combine (wldsB) visible
    // Seg1: g0 absorbs combine; g1 stages W_ctr2 into wldsA
    if (g == 0) {
        const float* comb = reinterpret_cast<const float*>(lds + 16384);
#pragma unroll
        for (int reg = 0; reg < 4; reg++)
#pragma unroll
            for (int nf = 0; nf < 8; nf++)
                acc[nf][reg] += comb[chunk * 2048 + (q * 4 + reg) * 128 + nf * 16 + p];
    } else {
        int slot = 62 + iter;
#pragma unroll
        for (int k = 0; k < 8; k++)
            *reinterpret_cast<bf16x8*>(lds + k * 2048 + tg * 8) =
                ld8(Wt + slot * 16384 + k * 2048 + tg * 8);
    }
    __syncthreads();
    // Seg2: g0 GN1 + relu -> bf16 transpose buffer (aliases wldsB, stride 136)
    unsigned short* tbuf = lds + 16384;
    if (g == 0) {
        float s[4], s2[4];
#pragma unroll
        for (int reg = 0; reg < 4; reg++) {
            s[reg] = 0.f; s2[reg] = 0.f;
#pragma unroll
            for (int nf = 0; nf < 8; nf++) { float v = acc[nf][reg]; s[reg] += v; s2[reg] += v * v; }
        }
#pragma unroll
        for (int m = 1; m <= 8; m <<= 1) {
#pragma unroll
            for (int reg = 0; reg < 4; reg++) {
                s[reg]  += __shfl_xor(s[reg],  m, 64);
                s2[reg] += __shfl_xor(s2[reg], m, 64);
            }
        }
#pragma unroll
        for (int reg = 0; reg < 4; reg++) {
            float mean = s[reg] * (1.f / 128.f);
            float var  = s2[reg] * (1.f / 128.f) - mean * mean;
            float rstd = rsqrtf(var + 1e-5f);
#pragma unroll
            for (int nf = 0; nf < 8; nf++) {
                float val = fmaxf((acc[nf][reg] - mean) * rstd * g1v[nf * 16 + p] + b1v[nf * 16 + p], 0.f);
                tbuf[chunk * 2176 + (q * 4 + reg) * 136 + nf * 16 + p] = f2bf(val);
            }
        }
    }
    __syncthreads();
    // Seg3: g0 ctr2 MFMA + GN2 + residual + relu -> dst
    if (g == 0) {
        bf16x8 a2[4];
#pragma unroll
        for (int ks = 0; ks < 4; ks++)
            a2[ks] = *reinterpret_cast<const bf16x8*>(tbuf + chunk * 2176 + p * 136 + ks * 32 + q * 8);
        f32x4 acc2[8];
#pragma unroll
        for (int nf = 0; nf < 8; nf++) acc2[nf] = (f32x4){0.f, 0.f, 0.f, 0.f};
#pragma unroll
        for (int ks = 0; ks < 4; ks++)
#pragma unroll
            for (int nf = 0; nf < 8; nf++) {
                bf16x8 bwf = *reinterpret_cast<const bf16x8*>(lds + ((ks * 8 + nf) * 64 + lane) * 8);
                acc2[nf] = __builtin_amdgcn_mfma_f32_16x16x32_bf16(a2[ks], bwf, acc2[nf], 0, 0, 0);
            }
        float s[4], s2[4];
#pragma unroll
        for (int reg = 0; reg < 4; reg++) {
            s[reg] = 0.f; s2[reg] = 0.f;
#pragma unroll
            for (int nf = 0; nf < 8; nf++) { float v = acc2[nf][reg]; s[reg] += v; s2[reg] += v * v; }
        }
#pragma unroll
        for (int m = 1; m <= 8; m <<= 1) {
#pragma unroll
            for (int reg = 0; reg < 4; reg++) {
                s[reg]  += __shfl_xor(s[reg],  m, 64);
                s2[reg] += __shfl_xor(s2[reg], m, 64);
            }
        }
#pragma unroll
        for (int reg = 0; reg < 4; reg++) {
            float mean = s[reg] * (1.f / 128.f);
            float var  = s2[reg] * (1.f / 128.f) - mean * mean;
            float rstd = rsqrtf(var + 1e-5f);
            int row = rb + q * 4 + reg;
#pragma unroll
            for (int nf = 0; nf < 8; nf++) {
                int col = nf * 16 + p;
                float val = (acc2[nf][reg] - mean) * rstd * g2v[col] + b2v[col]
                          + bf2f(src[row * 128 + col]);
                dst[row * 128 + col] = f2bf(fmaxf(val, 0.f));
            }
        }
    }
}

// ---------------------------------------------------------------------------
// Final cast: featA (bf16) -> d_out (fp32)
// ---------------------------------------------------------------------------
__global__ void k_copy(const unsigned short* __restrict__ srcb, float* __restrict__ out) {
    int t = blockIdx.x * 256 + threadIdx.x;    // one octet per thread
    bf16x8 v = ld8(srcb + t * 8);
    f32x4 lo, hi;
#pragma unroll
    for (int i = 0; i < 4; i++) { lo[i] = bf2f((unsigned short)v[i]); hi[i] = bf2f((unsigned short)v[i + 4]); }
    *reinterpret_cast<f32x4*>(out + t * 8)     = lo;
    *reinterpret_cast<f32x4*>(out + t * 8 + 4) = hi;
}

// ---------------------------------------------------------------------------
extern "C" void kernel_launch(void* const* d_in, const int* in_sizes, int n_in,
                              void* d_out, int out_size, void* d_ws, size_t ws_size,
                              hipStream_t stream) {
    (void)in_sizes; (void)n_in; (void)out_size; (void)ws_size;
    const float* ctrs   = (const float*)d_in[0];
    const float* feats  = (const float*)d_in[1];
    const float* Wi1    = (const float*)d_in[2];
    const float* bi1    = (const float*)d_in[3];
    const float* Wi2    = (const float*)d_in[4];
    const float* gi     = (const float*)d_in[5];
    const float* bi     = (const float*)d_in[6];
    const float* Ws1    = (const float*)d_in[7];
    const float* bs1    = (const float*)d_in[8];
    const float* Ws2    = (const float*)d_in[9];
    const float* gs     = (const float*)d_in[10];
    const float* bs     = (const float*)d_in[11];
    const float* W_ctr  = (const float*)d_in[12];
    const float* W_pre  = (const float*)d_in[13];
    const float* W_suc  = (const float*)d_in[14];
    const float* W_left = (const float*)d_in[15];
    const float* W_right= (const float*)d_in[16];
    const float* norm_g = (const float*)d_in[17];
    const float* norm_b = (const float*)d_in[18];
    const float* W_ctr2 = (const float*)d_in[19];
    const float* ctr2_g = (const float*)d_in[20];
    const float* ctr2_b = (const float*)d_in[21];
    const int* pre_u  = (const int*)d_in[22];
    const int* pre_v  = (const int*)d_in[23];
    const int* suc_u  = (const int*)d_in[24];
    const int* suc_v  = (const int*)d_in[25];
    const int* left_u = (const int*)d_in[26];
    const int* left_v = (const int*)d_in[27];
    const int* right_u= (const int*)d_in[28];
    const int* right_v= (const int*)d_in[29];

    // ws layout (85.8 MB total, same as round 4):
    //   Wt     @ 0          (2,162,688 B)
    //   off    @ 2,162,688  (11,200,016 B)   [cnt aliases off during histogram]
    //   eidx   @ 13,362,704 (10,000,000 B)
    //   featA  @ 23,362,704 (51,200,000 B)
    //   cursor @ 74,562,704 (11,200,016 B)   [dead after k_scatter]
    //   bsum   @ 85,762,720 (8,192 B)
    char* ws = (char*)d_ws;
    unsigned short* Wt    = (unsigned short*)ws;
    int*            off   = (int*)(ws + 2162688);
    int*            cnt   = off;
    int*            eidx  = (int*)(ws + 13362704);
    unsigned short* featA = (unsigned short*)(ws + 23362704);
    int*            cursor= (int*)(ws + 74562704);
    int*            bsum  = (int*)(ws + 85762720);

    float*          outF  = (float*)d_out;
    unsigned short* featB = (unsigned short*)d_out;   // bf16, lo half of d_out

    const int NB_SCAN = (MTOT + 2047) / 2048;   // 1368

    k_wt<<<66, 256, 0, stream>>>(Wi2, Ws2, W_ctr, W_pre, W_suc, W_left, W_right, W_ctr2, Wt);

    // Fused input stage -> featA (bf16)
    k_input<<<NN / 64, 256, 0, stream>>>(ctrs, feats, Wi1, bi1, gi, bi,
                                         Ws1, bs1, gs, bs, Wt, featA);

    // CSR build (ws scratch)
    hipMemsetAsync(cnt, 0, (MTOT + 1) * sizeof(int), stream);
    k_hist<<<(TOTE + 255) / 256, 256, 0, stream>>>(pre_u, suc_u, left_u, right_u, cnt);
    k_scan1<<<NB_SCAN, 256, 0, stream>>>(cnt, bsum);
    k_scan2<<<1, 64, 0, stream>>>(bsum, NB_SCAN);
    k_scan3<<<NB_SCAN, 256, 0, stream>>>(cnt, bsum, off, cursor);
    k_scatter<<<(TOTE + 255) / 256, 256, 0, stream>>>(pre_u, pre_v, suc_u, suc_v,
                                                      left_u, left_v, right_u, right_v,
                                                      cursor, eidx);

    // 4 fuse iterations, ping-pong featA (ws) <-> featB (d_out lo half)
    const unsigned short* fs[5] = { featA, featB, featA, featB, featA };
    for (int i = 0; i < 4; i++) {
        k_fuse<<<NN / 64, 512, 0, stream>>>(fs[i], (unsigned short*)fs[i + 1],
                                            off, eidx, Wt,
                                            norm_g + i * 128, norm_b + i * 128,
                                            ctr2_g + i * 128, ctr2_b + i * 128, i);
    }
    // final: featA -> fp32 d_out
    k_copy<<<NN * 128 / (256 * 8), 256, 0, stream>>>(featA, outF);
}